// Round 1
// baseline (1124.757 us; speedup 1.0000x reference)
//
#include <hip/hip_runtime.h>

typedef __attribute__((ext_vector_type(8))) __bf16 bf16x8;
typedef __attribute__((ext_vector_type(4))) float f32x4;

__device__ __forceinline__ ushort f2bf(float f) {
  union { float f; unsigned u; } x; x.f = f;
  unsigned r = x.u + 0x7FFFu + ((x.u >> 16) & 1u);
  return (ushort)(r >> 16);
}
__device__ __forceinline__ float bf2f(ushort u) {
  union { unsigned u; float f; } x; x.u = ((unsigned)u) << 16;
  return x.f;
}

__device__ __forceinline__ void gload_lds16(const void* g, void* l) {
  __builtin_amdgcn_global_load_lds(
      (const __attribute__((address_space(1))) void*)g,
      (__attribute__((address_space(3))) void*)l, 16, 0, 0);
}

// ---------------- fp32 -> bf16 convert ----------------
__global__ __launch_bounds__(256) void cvt_f32_bf16(const float4* __restrict__ in,
                                                    ushort4* __restrict__ out, int n4) {
  int i = blockIdx.x * 256 + threadIdx.x;
  if (i >= n4) return;
  float4 v = in[i];
  ushort4 o;
  o.x = f2bf(v.x); o.y = f2bf(v.y); o.z = f2bf(v.z); o.w = f2bf(v.w);
  out[i] = o;
}

// ---------------- generic B^T-form bf16 MFMA GEMM ----------------
// C[m,n] = (sum_k A[m,k]*B[n,k]) * (SCALED?scale:1) + bias
// A: rows m, K contiguous. B: rows n, K contiguous. grid: (M/128, N/128, batches)
// BIAS_MODE: 0 none, 1 bias[n], 2 bias[m].  OUT_BF16: 1 bf16, 0 fp32.
template<int OUT_BF16, int BIAS_MODE, int SCALED>
__global__ __launch_bounds__(256) void gemm_bt(
    const ushort* __restrict__ A, const ushort* __restrict__ B,
    void* __restrict__ Cv, const float* __restrict__ bias,
    int N, int K, long sA, long sB, long sC, float scale)
{
  __shared__ ushort At[2][128 * 32];
  __shared__ ushort Bt[2][128 * 32];
  const int bz = blockIdx.z;
  const ushort* Ab = A + (size_t)bz * sA;
  const ushort* Bb = B + (size_t)bz * sB;
  const int tile_m = blockIdx.x * 128;
  const int tile_n = blockIdx.y * 128;
  const int t = threadIdx.x;
  const int lane = t & 63;
  const int m_off = ((t >> 6) >> 1) * 64;
  const int n_off = ((t >> 6) & 1) * 64;

  f32x4 acc[4][4] = {};

  // stage a 128x32 bf16 tile (8KB) of A and B into LDS buffer p for k-offset k0
#define STAGE(p, k0)                                                                     \
  do {                                                                                   \
    for (int i = 0; i < 2; ++i) {                                                        \
      int o = t * 16 + i * 4096;                                                         \
      int r = o >> 6, cb = o & 63;                                                       \
      gload_lds16((const char*)(Ab + (size_t)(tile_m + r) * K + (k0)) + cb,              \
                  (char*)&At[p][0] + o);                                                 \
      gload_lds16((const char*)(Bb + (size_t)(tile_n + r) * K + (k0)) + cb,              \
                  (char*)&Bt[p][0] + o);                                                 \
    }                                                                                    \
  } while (0)

  STAGE(0, 0);
  const int KT = K >> 5;
  for (int kt = 0; kt < KT; ++kt) {
    const int p = kt & 1;
    __syncthreads();  // drains my global_load_lds (vmcnt0) + all waves' ds_reads of buf p^1
    if (kt + 1 < KT) STAGE(p ^ 1, (kt + 1) * 32);
    bf16x8 af[4], bfr[4];
#pragma unroll
    for (int x = 0; x < 4; ++x) {
      af[x]  = *(const bf16x8*)&At[p][(m_off + x * 16 + (lane & 15)) * 32 + (lane >> 4) * 8];
      bfr[x] = *(const bf16x8*)&Bt[p][(n_off + x * 16 + (lane & 15)) * 32 + (lane >> 4) * 8];
    }
#pragma unroll
    for (int mi = 0; mi < 4; ++mi)
#pragma unroll
      for (int ni = 0; ni < 4; ++ni)
        acc[mi][ni] = __builtin_amdgcn_mfma_f32_16x16x32_bf16(af[mi], bfr[ni], acc[mi][ni], 0, 0, 0);
  }
#undef STAGE

  // epilogue: C/D layout (verified): row = (lane>>4)*4 + j, col = lane&15
  const int r0 = tile_m + m_off + ((lane >> 4) * 4);
  const int c0 = tile_n + n_off + (lane & 15);
#pragma unroll
  for (int ni = 0; ni < 4; ++ni) {
    const int cc = c0 + ni * 16;
    float bc = 0.f;
    if (BIAS_MODE == 1) bc = bias[cc];
#pragma unroll
    for (int mi = 0; mi < 4; ++mi) {
#pragma unroll
      for (int j = 0; j < 4; ++j) {
        int rr = r0 + mi * 16 + j;
        float val = acc[mi][ni][j];
        if (SCALED) val *= scale;
        if (BIAS_MODE == 1) val += bc;
        else if (BIAS_MODE == 2) val += bias[rr];
        size_t idx = (size_t)bz * sC + (size_t)rr * N + cc;
        if (OUT_BF16) ((ushort*)Cv)[idx] = f2bf(val);
        else          ((float*)Cv)[idx] = val;
      }
    }
  }
}

// ---------------- column softmax over rows (axis = row index) ----------------
// S, P: [batch][rows][cols] bf16. softmax over r for each (batch, col).
__global__ __launch_bounds__(256) void col_softmax(const ushort* __restrict__ S,
                                                   ushort* __restrict__ P, int rows, int cols) {
  const int b = blockIdx.y;
  const size_t base = (size_t)b * rows * cols;
  const int c = threadIdx.x & 63;
  const int col = blockIdx.x * 64 + c;
  const int rg = threadIdx.x >> 6;
  float mx = -1e30f, sm = 0.f;
  for (int r = rg; r < rows; r += 4) {
    float v = bf2f(S[base + (size_t)r * cols + col]);
    float nm = fmaxf(mx, v);
    sm = sm * __expf(mx - nm) + __expf(v - nm);
    mx = nm;
  }
  __shared__ float smx[4][64], ssm[4][64];
  smx[rg][c] = mx; ssm[rg][c] = sm;
  __syncthreads();
  float M = fmaxf(fmaxf(smx[0][c], smx[1][c]), fmaxf(smx[2][c], smx[3][c]));
  float Z = ssm[0][c] * __expf(smx[0][c] - M) + ssm[1][c] * __expf(smx[1][c] - M) +
            ssm[2][c] * __expf(smx[2][c] - M) + ssm[3][c] * __expf(smx[3][c] - M);
  float invZ = 1.f / Z;
  for (int r = rg; r < rows; r += 4) {
    size_t idx = base + (size_t)r * cols + col;
    P[idx] = f2bf(__expf(bf2f(S[idx]) - M) * invZ);
  }
}

// ---------------- final: softmax over s per (b,d) + residual add ----------------
__global__ __launch_bounds__(256) void final_k(const float* __restrict__ attn,
                                               const float* __restrict__ q,
                                               float* __restrict__ out0,
                                               float* __restrict__ out1, int rows, int cols) {
  const int b = blockIdx.y;
  const size_t base = (size_t)b * rows * cols;
  const int c = threadIdx.x & 63;
  const int col = blockIdx.x * 64 + c;
  const int rg = threadIdx.x >> 6;
  float mx = -1e30f, sm = 0.f;
  for (int r = rg; r < rows; r += 4) {
    float v = attn[base + (size_t)r * cols + col];
    float nm = fmaxf(mx, v);
    sm = sm * __expf(mx - nm) + __expf(v - nm);
    mx = nm;
  }
  __shared__ float smx[4][64], ssm[4][64];
  smx[rg][c] = mx; ssm[rg][c] = sm;
  __syncthreads();
  float M = fmaxf(fmaxf(smx[0][c], smx[1][c]), fmaxf(smx[2][c], smx[3][c]));
  float Z = ssm[0][c] * __expf(smx[0][c] - M) + ssm[1][c] * __expf(smx[1][c] - M) +
            ssm[2][c] * __expf(smx[2][c] - M) + ssm[3][c] * __expf(smx[3][c] - M);
  float invZ = 1.f / Z;
  for (int r = rg; r < rows; r += 4) {
    size_t idx = base + (size_t)r * cols + col;
    float v = attn[idx];
    out1[idx] = __expf(v - M) * invZ;   // attn_w (pre-residual)
    out0[idx] = v + q[idx];             // attn + residual
  }
}

extern "C" void kernel_launch(void* const* d_in, const int* in_sizes, int n_in,
                              void* d_out, int out_size, void* d_ws, size_t ws_size,
                              hipStream_t stream) {
  const float* q  = (const float*)d_in[0];
  const float* k  = (const float*)d_in[1];
  const float* v  = (const float*)d_in[2];
  const float* Wq = (const float*)d_in[3];
  const float* bq = (const float*)d_in[4];
  const float* Wk = (const float*)d_in[5];
  const float* bk = (const float*)d_in[6];
  const float* Wv = (const float*)d_in[7];
  const float* bv = (const float*)d_in[8];
  float* out = (float*)d_out;

  const int B = 8, S = 2048, D = 1024;
  const long BS = (long)B * S;        // 16384
  const long nQKV = BS * D;           // 16,777,216 elements
  const long nW = (long)D * D;        // 1,048,576

  // bf16 staging of inputs lives in d_out (134MB; we use first ~102MB, final_k
  // fully overwrites d_out at the end).
  ushort* qb  = (ushort*)d_out;
  ushort* kb  = qb + nQKV;
  ushort* vb  = kb + nQKV;
  ushort* Wqb = vb + nQKV;
  ushort* Wkb = Wqb + nW;
  ushort* Wvb = Wkb + nW;

  // workspace map (peak 160 MiB):
  //  [0,32M)   qp bf16          -> later probs (first half)
  //  [32,64M)  kp bf16          -> later probs (second half)
  //  [64,96M)  vpT bf16 [b][e][s]
  //  [96,160M) scores bf16 [b][q][k] -> later attn fp32 [b][q][d]
  char* ws = (char*)d_ws;
  ushort* qp     = (ushort*)ws;
  ushort* kp     = (ushort*)(ws + (32ull << 20));
  ushort* vpT    = (ushort*)(ws + (64ull << 20));
  ushort* scores = (ushort*)(ws + (96ull << 20));
  ushort* probs  = (ushort*)ws;                    // over qp+kp (dead)
  float*  attn   = (float*)(ws + (96ull << 20));   // over scores (dead)

  auto cvt = [&](const float* src, ushort* dst, long n) {
    int n4 = (int)(n / 4);
    cvt_f32_bf16<<<dim3((n4 + 255) / 256), 256, 0, stream>>>((const float4*)src, (ushort4*)dst, n4);
  };
  cvt(q, qb, nQKV);
  cvt(k, kb, nQKV);
  cvt(v, vb, nQKV);
  cvt(Wq, Wqb, nW);
  cvt(Wk, Wkb, nW);
  cvt(Wv, Wvb, nW);

  // qp[m][e] = q[m][:]·Wq[e][:] + bq[e]
  gemm_bt<1, 1, 0><<<dim3(BS / 128, D / 128, 1), 256, 0, stream>>>(
      qb, Wqb, qp, bq, D, D, 0, 0, 0, 1.f);
  // kp[m][e]
  gemm_bt<1, 1, 0><<<dim3(BS / 128, D / 128, 1), 256, 0, stream>>>(
      kb, Wkb, kp, bk, D, D, 0, 0, 0, 1.f);
  // vpT[b][e][s] = Wv[e][:]·v[b][s][:] + bv[e]   (row bias)
  gemm_bt<1, 2, 0><<<dim3(D / 128, S / 128, B), 256, 0, stream>>>(
      Wvb, vb, vpT, bv, S, D, 0, (long)S * D, (long)D * S, 1.f);
  // scores[b][q][k] = qp[b][q][:]·kp[b][k][:] / 1024
  gemm_bt<1, 0, 1><<<dim3(S / 128, S / 128, B), 256, 0, stream>>>(
      qp, kp, scores, nullptr, S, D, (long)S * D, (long)S * D, (long)S * S, 1.f / 1024.f);
  // softmax over q (rows) for each (b, k column)
  col_softmax<<<dim3(S / 64, B), 256, 0, stream>>>(scores, probs, S, S);
  // attn[b][q][d] = probs[b][q][:]·vpT[b][d][:]   (fp32 out)
  gemm_bt<0, 0, 0><<<dim3(S / 128, D / 128, B), 256, 0, stream>>>(
      probs, vpT, attn, nullptr, D, S, (long)S * S, (long)D * S, (long)S * D, 1.f);
  // second softmax over s per (b,d), plus residual add
  final_k<<<dim3(D / 64, B), 256, 0, stream>>>(attn, q, out, out + nQKV, S, D);

  (void)in_sizes; (void)n_in; (void)out_size; (void)ws_size;
}

// Round 2
// 584.210 us; speedup vs baseline: 1.9253x; 1.9253x over previous
//
#include <hip/hip_runtime.h>

typedef __attribute__((ext_vector_type(8))) __bf16 bf16x8;
typedef __attribute__((ext_vector_type(4))) float f32x4;

__device__ __forceinline__ ushort f2bf(float f) {
  union { float f; unsigned u; } x; x.f = f;
  unsigned r = x.u + 0x7FFFu + ((x.u >> 16) & 1u);
  return (ushort)(r >> 16);
}
__device__ __forceinline__ float bf2f(ushort u) {
  union { unsigned u; float f; } x; x.u = ((unsigned)u) << 16;
  return x.f;
}

__device__ __forceinline__ void gload_lds16(const void* g, void* l) {
  __builtin_amdgcn_global_load_lds(
      (const __attribute__((address_space(1))) void*)g,
      (__attribute__((address_space(3))) void*)l, 16, 0, 0);
}

// ---------------- fp32 -> bf16 convert ----------------
__global__ __launch_bounds__(256) void cvt_f32_bf16(const float4* __restrict__ in,
                                                    ushort4* __restrict__ out, int n4) {
  int i = blockIdx.x * 256 + threadIdx.x;
  if (i >= n4) return;
  float4 v = in[i];
  ushort4 o;
  o.x = f2bf(v.x); o.y = f2bf(v.y); o.z = f2bf(v.z); o.w = f2bf(v.w);
  out[i] = o;
}

// ---------------- generic B^T-form bf16 MFMA GEMM ----------------
// C[m,n] = (sum_k A[m,k]*B[n,k]) * (SCALED?scale:1) + bias
// A: rows m, K contiguous. B: rows n, K contiguous. grid: (M/128, N/128, batches)
// BIAS_MODE: 0 none, 1 bias[n], 2 bias[m].  OUT_BF16: 1 bf16, 0 fp32.
template<int OUT_BF16, int BIAS_MODE, int SCALED>
__global__ __launch_bounds__(256) void gemm_bt(
    const ushort* __restrict__ A, const ushort* __restrict__ B,
    void* __restrict__ Cv, const float* __restrict__ bias,
    int N, int K, long sA, long sB, long sC, float scale)
{
  __shared__ ushort At[2][128 * 32];
  __shared__ ushort Bt[2][128 * 32];
  const int bz = blockIdx.z;
  const ushort* Ab = A + (size_t)bz * sA;
  const ushort* Bb = B + (size_t)bz * sB;
  const int tile_m = blockIdx.x * 128;
  const int tile_n = blockIdx.y * 128;
  const int t = threadIdx.x;
  const int lane = t & 63;
  const int m_off = ((t >> 6) >> 1) * 64;
  const int n_off = ((t >> 6) & 1) * 64;

  f32x4 acc[4][4] = {};

#define STAGE(p, k0)                                                                     \
  do {                                                                                   \
    for (int i = 0; i < 2; ++i) {                                                        \
      int o = t * 16 + i * 4096;                                                         \
      int r = o >> 6, cb = o & 63;                                                       \
      gload_lds16((const char*)(Ab + (size_t)(tile_m + r) * K + (k0)) + cb,              \
                  (char*)&At[p][0] + o);                                                 \
      gload_lds16((const char*)(Bb + (size_t)(tile_n + r) * K + (k0)) + cb,              \
                  (char*)&Bt[p][0] + o);                                                 \
    }                                                                                    \
  } while (0)

  STAGE(0, 0);
  const int KT = K >> 5;
  for (int kt = 0; kt < KT; ++kt) {
    const int p = kt & 1;
    __syncthreads();
    if (kt + 1 < KT) STAGE(p ^ 1, (kt + 1) * 32);
    bf16x8 af[4], bfr[4];
#pragma unroll
    for (int x = 0; x < 4; ++x) {
      af[x]  = *(const bf16x8*)&At[p][(m_off + x * 16 + (lane & 15)) * 32 + (lane >> 4) * 8];
      bfr[x] = *(const bf16x8*)&Bt[p][(n_off + x * 16 + (lane & 15)) * 32 + (lane >> 4) * 8];
    }
#pragma unroll
    for (int mi = 0; mi < 4; ++mi)
#pragma unroll
      for (int ni = 0; ni < 4; ++ni)
        acc[mi][ni] = __builtin_amdgcn_mfma_f32_16x16x32_bf16(af[mi], bfr[ni], acc[mi][ni], 0, 0, 0);
  }
#undef STAGE

  const int r0 = tile_m + m_off + ((lane >> 4) * 4);
  const int c0 = tile_n + n_off + (lane & 15);
#pragma unroll
  for (int ni = 0; ni < 4; ++ni) {
    const int cc = c0 + ni * 16;
    float bc = 0.f;
    if (BIAS_MODE == 1) bc = bias[cc];
#pragma unroll
    for (int mi = 0; mi < 4; ++mi) {
#pragma unroll
      for (int j = 0; j < 4; ++j) {
        int rr = r0 + mi * 16 + j;
        float val = acc[mi][ni][j];
        if (SCALED) val *= scale;
        if (BIAS_MODE == 1) val += bc;
        else if (BIAS_MODE == 2) val += bias[rr];
        size_t idx = (size_t)bz * sC + (size_t)rr * N + cc;
        if (OUT_BF16) ((ushort*)Cv)[idx] = f2bf(val);
        else          ((float*)Cv)[idx] = val;
      }
    }
  }
}

// ============ chunked column softmax (softmax over ROW axis per column) ============
// pass1: per-chunk online (max,sum) per column. grid: (cols/1024, B, rows/RPC)
// thread handles 4 consecutive cols.
template<int BF16IN>
__global__ __launch_bounds__(256) void colsm_pass1(
    const void* __restrict__ X, float* __restrict__ red_max, float* __restrict__ red_sum,
    int rows, int cols, int rpc)
{
  const int b = blockIdx.y;
  const int nch = gridDim.z;
  const int ch = blockIdx.z;
  const size_t base = (size_t)b * rows * cols;
  const int c4 = (blockIdx.x * 256 + threadIdx.x) * 4;
  const int r0 = ch * rpc;
  float mx[4] = {-1e30f, -1e30f, -1e30f, -1e30f};
  float sm[4] = {0.f, 0.f, 0.f, 0.f};
  for (int r = r0; r < r0 + rpc; ++r) {
    float v[4];
    if (BF16IN) {
      ushort4 u = *(const ushort4*)((const ushort*)X + base + (size_t)r * cols + c4);
      v[0] = bf2f(u.x); v[1] = bf2f(u.y); v[2] = bf2f(u.z); v[3] = bf2f(u.w);
    } else {
      float4 u = *(const float4*)((const float*)X + base + (size_t)r * cols + c4);
      v[0] = u.x; v[1] = u.y; v[2] = u.z; v[3] = u.w;
    }
#pragma unroll
    for (int i = 0; i < 4; ++i) {
      float nm = fmaxf(mx[i], v[i]);
      sm[i] = sm[i] * __expf(mx[i] - nm) + __expf(v[i] - nm);
      mx[i] = nm;
    }
  }
  size_t ro = ((size_t)b * nch + ch) * cols + c4;
#pragma unroll
  for (int i = 0; i < 4; ++i) { red_max[ro + i] = mx[i]; red_sum[ro + i] = sm[i]; }
}

// combine partials -> M, 1/Z per (b,col). grid: (cols/256, B)
__global__ __launch_bounds__(256) void colsm_combine(
    const float* __restrict__ red_max, const float* __restrict__ red_sum,
    float* __restrict__ Mv, float* __restrict__ Zinv, int cols, int nch)
{
  const int b = blockIdx.y;
  const int c = blockIdx.x * 256 + threadIdx.x;
  float M = -1e30f, Z = 0.f;
  for (int ch = 0; ch < nch; ++ch) {
    size_t o = ((size_t)b * nch + ch) * cols + c;
    float m = red_max[o], s = red_sum[o];
    float nm = fmaxf(M, m);
    Z = Z * __expf(M - nm) + s * __expf(m - nm);
    M = nm;
  }
  Mv[(size_t)b * cols + c] = M;
  Zinv[(size_t)b * cols + c] = 1.f / Z;
}

// emit bf16 probs. grid like pass1.
__global__ __launch_bounds__(256) void colsm_emit_bf16(
    const ushort* __restrict__ X, ushort* __restrict__ P,
    const float* __restrict__ Mv, const float* __restrict__ Zinv,
    int rows, int cols, int rpc)
{
  const int b = blockIdx.y;
  const int ch = blockIdx.z;
  const size_t base = (size_t)b * rows * cols;
  const int c4 = (blockIdx.x * 256 + threadIdx.x) * 4;
  const int r0 = ch * rpc;
  float M[4], Zi[4];
#pragma unroll
  for (int i = 0; i < 4; ++i) {
    M[i] = Mv[(size_t)b * cols + c4 + i];
    Zi[i] = Zinv[(size_t)b * cols + c4 + i];
  }
  for (int r = r0; r < r0 + rpc; ++r) {
    size_t o = base + (size_t)r * cols + c4;
    ushort4 u = *(const ushort4*)(X + o);
    ushort4 w;
    w.x = f2bf(__expf(bf2f(u.x) - M[0]) * Zi[0]);
    w.y = f2bf(__expf(bf2f(u.y) - M[1]) * Zi[1]);
    w.z = f2bf(__expf(bf2f(u.z) - M[2]) * Zi[2]);
    w.w = f2bf(__expf(bf2f(u.w) - M[3]) * Zi[3]);
    *(ushort4*)(P + o) = w;
  }
}

// final emit: out1 = softmax(attn over rows), out0 = attn + residual. grid like pass1.
__global__ __launch_bounds__(256) void final_emit(
    const float* __restrict__ attn, const float* __restrict__ q,
    float* __restrict__ out0, float* __restrict__ out1,
    const float* __restrict__ Mv, const float* __restrict__ Zinv,
    int rows, int cols, int rpc)
{
  const int b = blockIdx.y;
  const int ch = blockIdx.z;
  const size_t base = (size_t)b * rows * cols;
  const int c4 = (blockIdx.x * 256 + threadIdx.x) * 4;
  const int r0 = ch * rpc;
  float M[4], Zi[4];
#pragma unroll
  for (int i = 0; i < 4; ++i) {
    M[i] = Mv[(size_t)b * cols + c4 + i];
    Zi[i] = Zinv[(size_t)b * cols + c4 + i];
  }
  for (int r = r0; r < r0 + rpc; ++r) {
    size_t o = base + (size_t)r * cols + c4;
    float4 a = *(const float4*)(attn + o);
    float4 qv = *(const float4*)(q + o);
    float4 w, s;
    w.x = __expf(a.x - M[0]) * Zi[0];
    w.y = __expf(a.y - M[1]) * Zi[1];
    w.z = __expf(a.z - M[2]) * Zi[2];
    w.w = __expf(a.w - M[3]) * Zi[3];
    s.x = a.x + qv.x; s.y = a.y + qv.y; s.z = a.z + qv.z; s.w = a.w + qv.w;
    *(float4*)(out1 + o) = w;
    *(float4*)(out0 + o) = s;
  }
}

extern "C" void kernel_launch(void* const* d_in, const int* in_sizes, int n_in,
                              void* d_out, int out_size, void* d_ws, size_t ws_size,
                              hipStream_t stream) {
  const float* q  = (const float*)d_in[0];
  const float* k  = (const float*)d_in[1];
  const float* v  = (const float*)d_in[2];
  const float* Wq = (const float*)d_in[3];
  const float* bq = (const float*)d_in[4];
  const float* Wk = (const float*)d_in[5];
  const float* bk = (const float*)d_in[6];
  const float* Wv = (const float*)d_in[7];
  const float* bv = (const float*)d_in[8];
  float* out = (float*)d_out;

  const int B = 8, S = 2048, D = 1024;
  const long BS = (long)B * S;        // 16384
  const long nQKV = BS * D;           // 16,777,216 elements
  const long nW = (long)D * D;

  // bf16 staging of inputs lives in d_out (dead once the scores GEMM is done).
  ushort* qb  = (ushort*)d_out;
  ushort* kb  = qb + nQKV;
  ushort* vb  = kb + nQKV;
  ushort* Wqb = vb + nQKV;
  ushort* Wkb = Wqb + nW;
  ushort* Wvb = Wkb + nW;

  // workspace map (peak 160 MiB):
  //  [0,32M)   qp bf16          -> later probs (first half) -> later red_f/Mf
  //  [32,64M)  kp bf16          -> later probs (second half)
  //  [64,96M)  vpT bf16 [b][e][s]
  //  [96,160M) scores bf16 [b][q][k] -> later attn fp32 [b][q][d]
  char* ws = (char*)d_ws;
  ushort* qp     = (ushort*)ws;
  ushort* kp     = (ushort*)(ws + (32ull << 20));
  ushort* vpT    = (ushort*)(ws + (64ull << 20));
  ushort* scores = (ushort*)(ws + (96ull << 20));
  ushort* probs  = (ushort*)ws;                    // over qp+kp (dead)
  float*  attn   = (float*)(ws + (96ull << 20));   // over scores (dead)

  const int RPC = 16;                 // rows per chunk
  const int NCH = S / RPC;            // 128 chunks

  // scores-softmax partials live in d_out (staging is dead by then; final_emit
  // overwrites all of d_out afterwards).
  float* red_s_max = (float*)d_out;                           // 8*128*2048 = 8MB
  float* red_s_sum = red_s_max + (size_t)B * NCH * S;         // 8MB
  float* Ms        = red_s_sum + (size_t)B * NCH * S;         // 64KB
  float* Zs        = Ms + (size_t)B * S;

  // final-softmax partials live in ws[0,64M) (probs dead after PV GEMM).
  float* red_f_max = (float*)ws;                              // 8*128*1024 = 4MB
  float* red_f_sum = red_f_max + (size_t)B * NCH * D;
  float* Mf        = red_f_sum + (size_t)B * NCH * D;
  float* Zf        = Mf + (size_t)B * D;

  auto cvt = [&](const float* src, ushort* dst, long n) {
    int n4 = (int)(n / 4);
    cvt_f32_bf16<<<dim3((n4 + 255) / 256), 256, 0, stream>>>((const float4*)src, (ushort4*)dst, n4);
  };
  cvt(q, qb, nQKV);
  cvt(k, kb, nQKV);
  cvt(v, vb, nQKV);
  cvt(Wq, Wqb, nW);
  cvt(Wk, Wkb, nW);
  cvt(Wv, Wvb, nW);

  // qp[m][e] = q[m][:]·Wq[e][:] + bq[e]
  gemm_bt<1, 1, 0><<<dim3(BS / 128, D / 128, 1), 256, 0, stream>>>(
      qb, Wqb, qp, bq, D, D, 0, 0, 0, 1.f);
  // kp[m][e]
  gemm_bt<1, 1, 0><<<dim3(BS / 128, D / 128, 1), 256, 0, stream>>>(
      kb, Wkb, kp, bk, D, D, 0, 0, 0, 1.f);
  // vpT[b][e][s] = Wv[e][:]·v[b][s][:] + bv[e]   (row bias)
  gemm_bt<1, 2, 0><<<dim3(D / 128, S / 128, B), 256, 0, stream>>>(
      Wvb, vb, vpT, bv, S, D, 0, (long)S * D, (long)D * S, 1.f);
  // scores[b][q][k] = qp[b][q][:]·kp[b][k][:] / 1024
  gemm_bt<1, 0, 1><<<dim3(S / 128, S / 128, B), 256, 0, stream>>>(
      qp, kp, scores, nullptr, S, D, (long)S * D, (long)S * D, (long)S * S, 1.f / 1024.f);

  // softmax over q (rows) for each (b, k column): 3-kernel chunked
  colsm_pass1<1><<<dim3(S / 1024, B, NCH), 256, 0, stream>>>(
      scores, red_s_max, red_s_sum, S, S, RPC);
  colsm_combine<<<dim3(S / 256, B), 256, 0, stream>>>(red_s_max, red_s_sum, Ms, Zs, S, NCH);
  colsm_emit_bf16<<<dim3(S / 1024, B, NCH), 256, 0, stream>>>(
      scores, probs, Ms, Zs, S, S, RPC);

  // attn[b][q][d] = probs[b][q][:]·vpT[b][d][:]   (fp32 out)
  gemm_bt<0, 0, 0><<<dim3(S / 128, D / 128, B), 256, 0, stream>>>(
      probs, vpT, attn, nullptr, D, S, (long)S * S, (long)D * S, (long)S * D, 1.f);

  // second softmax over s per (b,d) + residual: 3-kernel chunked
  colsm_pass1<0><<<dim3(D / 1024, B, NCH), 256, 0, stream>>>(
      attn, red_f_max, red_f_sum, S, D, RPC);
  colsm_combine<<<dim3(D / 256, B), 256, 0, stream>>>(red_f_max, red_f_sum, Mf, Zf, D, NCH);
  final_emit<<<dim3(D / 1024, B, NCH), 256, 0, stream>>>(
      attn, q, out, out + nQKV, Mf, Zf, S, D, RPC);

  (void)in_sizes; (void)n_in; (void)out_size; (void)ws_size;
}